// Round 15
// baseline (285.760 us; speedup 1.0000x reference)
//
#include <hip/hip_runtime.h>
#include <hip/hip_bf16.h>

#define NN 50000
#define EE 800000

typedef short short8 __attribute__((ext_vector_type(8)));
typedef float f32x4 __attribute__((ext_vector_type(4)));

union Frag16B { short8 s; int4 i; };
union H4 { _Float16 h[4]; uint2 u; };

static __device__ __forceinline__ unsigned short f2bf(float f) {
    union { float f; unsigned u; } v; v.f = f;
    unsigned r = v.u + 0x7FFF + ((v.u >> 16) & 1);   // RNE
    return (unsigned short)(r >> 16);
}
static __device__ __forceinline__ float bf_lo(unsigned int u) {
    return __uint_as_float(u << 16);
}
static __device__ __forceinline__ float bf_hi(unsigned int u) {
    return __uint_as_float(u & 0xFFFF0000u);
}
static __device__ __forceinline__ unsigned int pack2(float a, float b) {
    return (unsigned int)f2bf(a) | ((unsigned int)f2bf(b) << 16);
}

// ---------------- prep: weight packing + pos->float4 + workspace zeroing ----
__global__ __launch_bounds__(256) void k_prep(
    const float* __restrict__ w1,  const float* __restrict__ att,
    const float* __restrict__ w2,
    const float* __restrict__ wft, const float* __restrict__ wcv,
    const float* __restrict__ pos,
    unsigned short* __restrict__ w1p, unsigned short* __restrict__ w2p,
    unsigned short* __restrict__ wftp, unsigned short* __restrict__ wcvp,
    float4* __restrict__ pos4,
    int* __restrict__ counts, float* __restrict__ bn_psum, float* __restrict__ bn_psq)
{
    int gth = blockIdx.x * 256 + threadIdx.x;
    int lane = gth & 63, l15 = lane & 15, gg = lane >> 4;
    if (gth < 16384) {                       // w1p: kk<16, t<16, fold att[col]
        int t = (gth >> 6) & 15, kk = gth >> 10;
        int row = t * 16 + l15, c0 = kk * 32 + gg * 8;
        unsigned int pk[4];
        #pragma unroll
        for (int j = 0; j < 4; ++j) {
            int c = c0 + 2 * j;
            pk[j] = pack2(w1[row * 512 + c] * att[c],
                          w1[row * 512 + c + 1] * att[c + 1]);
        }
        *reinterpret_cast<uint4*>(w1p + (size_t)gth * 8) = make_uint4(pk[0], pk[1], pk[2], pk[3]);
        bn_psum[gth] = 0.f;
        bn_psq[gth] = 0.f;
    }
    if (gth < 4096) {                        // w2p: kk<8, t<8
        int t = (gth >> 6) & 7, kk = gth >> 9;
        int row = t * 16 + l15, c0 = kk * 32 + gg * 8;
        unsigned int pk[4];
        #pragma unroll
        for (int j = 0; j < 4; ++j) {
            int c = c0 + 2 * j;
            pk[j] = pack2(w2[row * 256 + c], w2[row * 256 + c + 1]);
        }
        *reinterpret_cast<uint4*>(w2p + (size_t)gth * 8) = make_uint4(pk[0], pk[1], pk[2], pk[3]);
    }
    if (gth < 2048) {                        // wftp / wcvp: kk<4, t<8
        int t = (gth >> 6) & 7, kk = gth >> 9;
        int row = t * 16 + l15, c0 = kk * 32 + gg * 8;
        unsigned int pa[4], pb[4];
        #pragma unroll
        for (int j = 0; j < 4; ++j) {
            int c = c0 + 2 * j;
            pa[j] = pack2(wft[row * 128 + c], wft[row * 128 + c + 1]);
            pb[j] = pack2(wcv[row * 128 + c], wcv[row * 128 + c + 1]);
        }
        *reinterpret_cast<uint4*>(wftp + (size_t)gth * 8) = make_uint4(pa[0], pa[1], pa[2], pa[3]);
        *reinterpret_cast<uint4*>(wcvp + (size_t)gth * 8) = make_uint4(pb[0], pb[1], pb[2], pb[3]);
    }
    if (gth < NN) {                          // pos -> padded float4; zero counts
        pos4[gth] = make_float4(pos[gth * 3 + 0], pos[gth * 3 + 1], pos[gth * 3 + 2], 0.f);
        counts[gth] = 0;
    }
}

// ---------------- fused node GEMMs (MFMA): msg = (relu(x WftT+bft)) WcvT + bcv
// Col-split remap (R12): wave w owns ALL 64 rows x its col-quarter.
__global__ __launch_bounds__(256) void k_ft_conv(
    const float* __restrict__ x,
    const unsigned short* __restrict__ wftp, const float* __restrict__ bft,
    const unsigned short* __restrict__ wcvp, const float* __restrict__ bcv,
    unsigned int* __restrict__ msg)          // bf16 [NN][128] as uint[NN][64]
{
    __shared__ unsigned int s_x[64 * 68];    // bf16 tile (reused for out)
    __shared__ unsigned short s_h[64 * 136];
    const int tid = threadIdx.x;
    const int w = tid >> 6, lane = tid & 63, l15 = lane & 15, g = lane >> 4;
    const int n0 = blockIdx.x * 64;

    #pragma unroll
    for (int i = 0; i < 8; ++i) {
        int lin = tid + i * 256;
        int row = lin >> 5, c4 = lin & 31;
        int ar = (n0 + row < NN) ? n0 + row : NN - 1;
        float4 v = *reinterpret_cast<const float4*>(x + (size_t)ar * 128 + c4 * 4);
        s_x[row * 68 + c4 * 2]     = pack2(v.x, v.y);
        s_x[row * 68 + c4 * 2 + 1] = pack2(v.z, v.w);
    }
    __syncthreads();

    float bftv[2], bcvv[2];
    #pragma unroll
    for (int t = 0; t < 2; ++t) {
        bftv[t] = bft[(w * 2 + t) * 16 + l15];
        bcvv[t] = bcv[(w * 2 + t) * 16 + l15];
    }

    const int4* Bf = reinterpret_cast<const int4*>(wftp);
    f32x4 acc[8];                            // [rt*2 + t]
    #pragma unroll
    for (int i = 0; i < 8; ++i) acc[i] = (f32x4){0.f, 0.f, 0.f, 0.f};
    #pragma unroll
    for (int kk = 0; kk < 4; ++kk) {
        Frag16B b[2];
        #pragma unroll
        for (int t = 0; t < 2; ++t)
            b[t].i = Bf[(kk * 8 + w * 2 + t) * 64 + lane];
        Frag16B a[4];
        #pragma unroll
        for (int rt = 0; rt < 4; ++rt)
            a[rt].i = *reinterpret_cast<const int4*>(
                &s_x[(rt * 16 + l15) * 68 + kk * 16 + g * 4]);
        #pragma unroll
        for (int rt = 0; rt < 4; ++rt)
            #pragma unroll
            for (int t = 0; t < 2; ++t)
                acc[rt * 2 + t] = __builtin_amdgcn_mfma_f32_16x16x32_bf16(
                    a[rt].s, b[t].s, acc[rt * 2 + t], 0, 0, 0);
    }
    #pragma unroll
    for (int rt = 0; rt < 4; ++rt)
        #pragma unroll
        for (int t = 0; t < 2; ++t)
            #pragma unroll
            for (int r = 0; r < 4; ++r)
                s_h[(rt * 16 + g * 4 + r) * 136 + (w * 2 + t) * 16 + l15] =
                    f2bf(fmaxf(acc[rt * 2 + t][r] + bftv[t], 0.f));
    __syncthreads();

    const int4* Bc = reinterpret_cast<const int4*>(wcvp);
    #pragma unroll
    for (int i = 0; i < 8; ++i) acc[i] = (f32x4){0.f, 0.f, 0.f, 0.f};
    #pragma unroll
    for (int kk = 0; kk < 4; ++kk) {
        Frag16B b[2];
        #pragma unroll
        for (int t = 0; t < 2; ++t)
            b[t].i = Bc[(kk * 8 + w * 2 + t) * 64 + lane];
        Frag16B a[4];
        #pragma unroll
        for (int rt = 0; rt < 4; ++rt)
            a[rt].i = *reinterpret_cast<const int4*>(
                &s_h[(rt * 16 + l15) * 136 + kk * 32 + g * 8]);
        #pragma unroll
        for (int rt = 0; rt < 4; ++rt)
            #pragma unroll
            for (int t = 0; t < 2; ++t)
                acc[rt * 2 + t] = __builtin_amdgcn_mfma_f32_16x16x32_bf16(
                    a[rt].s, b[t].s, acc[rt * 2 + t], 0, 0, 0);
    }
    unsigned short* s_o = reinterpret_cast<unsigned short*>(s_x);
    #pragma unroll
    for (int rt = 0; rt < 4; ++rt)
        #pragma unroll
        for (int t = 0; t < 2; ++t)
            #pragma unroll
            for (int r = 0; r < 4; ++r)
                s_o[(rt * 16 + g * 4 + r) * 136 + (w * 2 + t) * 16 + l15] =
                    f2bf(acc[rt * 2 + t][r] + bcvv[t]);
    __syncthreads();
    #pragma unroll
    for (int i = 0; i < 8; ++i) {
        int lin = tid + i * 256;
        int row = lin >> 5, cu2 = lin & 31;
        if (n0 + row < NN) {
            uint2 v;
            v.x = s_x[row * 68 + cu2 * 2];
            v.y = s_x[row * 68 + cu2 * 2 + 1];
            *reinterpret_cast<uint2*>(msg + (size_t)(n0 + row) * 64 + cu2 * 2) = v;
        }
    }
}

// ---------------- edge pass 1: degree + rank capture + block max ------------
__global__ __launch_bounds__(256) void k_edge_pass1(
    const int* __restrict__ ei, const float4* __restrict__ pos4,
    float* __restrict__ blockmax, int* __restrict__ counts,
    int* __restrict__ rank)
{
    __shared__ float smax[4];
    int e = blockIdx.x * 256 + threadIdx.x;       // grid covers EE exactly
    int s = ei[e], d = ei[EE + e];
    float4 ps = pos4[s], pd = pos4[d];
    float dx = ps.x - pd.x, dy = ps.y - pd.y, dz = ps.z - pd.z;
    float dist = sqrtf(dx * dx + dy * dy + dz * dz);
    rank[e] = atomicAdd(&counts[d], 1);

    float m = dist;
    #pragma unroll
    for (int o = 32; o >= 1; o >>= 1)
        m = fmaxf(m, __shfl_xor(m, o));
    if ((threadIdx.x & 63) == 0) smax[threadIdx.x >> 6] = m;
    __syncthreads();
    if (threadIdx.x == 0)
        blockmax[blockIdx.x] = fmaxf(fmaxf(smax[0], smax[1]), fmaxf(smax[2], smax[3]));
}

// ---------------- scan 1: per-block inclusive scan of counts ----------------
__global__ __launch_bounds__(256) void k_scan1(const int* __restrict__ counts,
    int* __restrict__ loc, int* __restrict__ bsum)
{
    __shared__ int sd[256];
    int i = blockIdx.x * 256 + threadIdx.x;
    int v = (i < NN) ? counts[i] : 0;
    sd[threadIdx.x] = v;
    __syncthreads();
    for (int ofs = 1; ofs < 256; ofs <<= 1) {
        int t = (threadIdx.x >= ofs) ? sd[threadIdx.x - ofs] : 0;
        __syncthreads();
        sd[threadIdx.x] += t;
        __syncthreads();
    }
    int incl = sd[threadIdx.x];
    if (i < NN) loc[i] = incl - v;
    if (threadIdx.x == 255) bsum[blockIdx.x] = incl;
}

// ---------------- scan 2 (merged): offs with inline bofs + dmax block -------
__global__ __launch_bounds__(256) void k_scan3(const int* __restrict__ loc,
    const int* __restrict__ bsum, const float* __restrict__ blockmax,
    int* __restrict__ offs, float* __restrict__ dmax, int nmb)
{
    if (blockIdx.x < 196) {
        __shared__ int sd[256];
        __shared__ int s_v[256];
        int v = (threadIdx.x < 196) ? bsum[threadIdx.x] : 0;
        sd[threadIdx.x] = v;
        s_v[threadIdx.x] = v;
        __syncthreads();
        for (int ofs = 1; ofs < 256; ofs <<= 1) {
            int t = (threadIdx.x >= ofs) ? sd[threadIdx.x - ofs] : 0;
            __syncthreads();
            sd[threadIdx.x] += t;
            __syncthreads();
        }
        int bofs = sd[blockIdx.x] - s_v[blockIdx.x];   // exclusive prefix at this block
        int i = blockIdx.x * 256 + threadIdx.x;
        if (i < NN) offs[i] = loc[i] + bofs;
        if (i == 0) offs[NN] = EE;
    } else {
        __shared__ float smax[4];
        float m = 0.f;
        for (int i = threadIdx.x; i < nmb; i += 256) m = fmaxf(m, blockmax[i]);
        #pragma unroll
        for (int o = 32; o >= 1; o >>= 1)
            m = fmaxf(m, __shfl_xor(m, o));
        if ((threadIdx.x & 63) == 0) smax[threadIdx.x >> 6] = m;
        __syncthreads();
        if (threadIdx.x == 0)
            dmax[0] = fmaxf(fmaxf(smax[0], smax[1]), fmaxf(smax[2], smax[3]));
    }
}

// ---------------- edge pass 2: geometry + ab + AoS CSR record ---------------
__global__ __launch_bounds__(256) void k_fill(
    const int* __restrict__ ei, const float4* __restrict__ pos4,
    const float* __restrict__ dmaxp,
    const float* __restrict__ vfp, const float* __restrict__ vpar,
    const int* __restrict__ offs, const int* __restrict__ rank,
    uint4* __restrict__ csre)
{
    int e = blockIdx.x * 256 + threadIdx.x;       // grid covers EE exactly
    int s = ei[e], d = ei[EE + e];
    float4 ps = pos4[s], pd = pos4[d];
    float dx = ps.x - pd.x, dy = ps.y - pd.y, dz = ps.z - pd.z;
    float dist = sqrtf(dx * dx + dy * dy + dz * dz);
    float rinv = 1.f / (dist + 1e-8f);
    float dsum = (dx + dy + dz) * rinv;
    float r = dist / dmaxp[0];
    float vf = vfp[0];
    H4 p;
    #pragma unroll
    for (int k = 0; k < 4; ++k) {
        float v = vf * fminf(r, vpar[k]);
        p.h[k] = (_Float16)(sqrtf(1.f - v * v + 1e-8f) / (1.f + v * dsum));
    }
    int slot = offs[d] + rank[e];
    csre[slot] = make_uint4((unsigned)s, p.u.x, p.u.y, 0u);
}

// ---------------- aggregation + fused BN partial stats ----------------------
// R8 structure (locally converged). AoS csre records, wave-uniform indices.
__global__ __launch_bounds__(256) void k_agg(
    const int* __restrict__ offs, const uint4* __restrict__ csre,
    const unsigned int* __restrict__ msg,
    unsigned int* __restrict__ aggb,         // bf16 [NN][512] as uint[NN][256]
    float* __restrict__ bn_psum, float* __restrict__ bn_psq)
{
    __shared__ float s_bn[4 * 1024];         // [wave][16 vals][64 lanes]
    const int tid = threadIdx.x;
    const int lane = tid & 63;
    const int w = __builtin_amdgcn_readfirstlane(tid >> 6);
    const int gw = (blockIdx.x << 2) | w;    // 0..8191

    float ps0 = 0, ps1 = 0, ps2 = 0, ps3 = 0, ps4 = 0, ps5 = 0, ps6 = 0, ps7 = 0;
    float pq0 = 0, pq1 = 0, pq2 = 0, pq3 = 0, pq4 = 0, pq5 = 0, pq6 = 0, pq7 = 0;

    for (int n = gw; n < NN; n += 8192) {
        int st = __builtin_amdgcn_readfirstlane(offs[n]);
        int en = __builtin_amdgcn_readfirstlane(offs[n + 1]);
        float a00 = 0, a10 = 0, a20 = 0, a30 = 0, a01 = 0, a11 = 0, a21 = 0, a31 = 0;

        for (int e = st; e < en; e += 8) {
            int idx[8];
            uint4 rr[8];
            unsigned int uu[8];
            #pragma unroll
            for (int j = 0; j < 8; ++j) {
                int ee = e + j;
                idx[j] = (ee < en) ? ee : en - 1;       // wave-uniform clamp
            }
            #pragma unroll
            for (int j = 0; j < 8; ++j) rr[j] = csre[idx[j]];
            #pragma unroll
            for (int j = 0; j < 8; ++j)
                uu[j] = msg[(size_t)rr[j].x * 64 + lane];
            #pragma unroll
            for (int j = 0; j < 8; ++j) {
                bool valid = (e + j) < en;              // wave-uniform
                H4 p;
                p.u.x = valid ? rr[j].y : 0u;
                p.u.y = valid ? rr[j].z : 0u;
                float m0 = bf_lo(uu[j]), m1 = bf_hi(uu[j]);
                a00 = fmaf((float)p.h[0], m0, a00); a01 = fmaf((float)p.h[0], m1, a01);
                a10 = fmaf((float)p.h[1], m0, a10); a11 = fmaf((float)p.h[1], m1, a11);
                a20 = fmaf((float)p.h[2], m0, a20); a21 = fmaf((float)p.h[2], m1, a21);
                a30 = fmaf((float)p.h[3], m0, a30); a31 = fmaf((float)p.h[3], m1, a31);
            }
        }

        unsigned int* o = aggb + (size_t)n * 256 + lane;   // col c = k*128 + h
        o[0]   = pack2(a00, a01);
        o[64]  = pack2(a10, a11);
        o[128] = pack2(a20, a21);
        o[192] = pack2(a30, a31);

        ps0 += a00; pq0 = fmaf(a00, a00, pq0);
        ps1 += a01; pq1 = fmaf(a01, a01, pq1);
        ps2 += a10; pq2 = fmaf(a10, a10, pq2);
        ps3 += a11; pq3 = fmaf(a11, a11, pq3);
        ps4 += a20; pq4 = fmaf(a20, a20, pq4);
        ps5 += a21; pq5 = fmaf(a21, a21, pq5);
        ps6 += a30; pq6 = fmaf(a30, a30, pq6);
        ps7 += a31; pq7 = fmaf(a31, a31, pq7);
    }

    // per-wave partials -> LDS
    float* sw = s_bn + w * 1024 + lane;
    sw[0 * 64] = ps0; sw[1 * 64] = ps1; sw[2 * 64] = ps2; sw[3 * 64] = ps3;
    sw[4 * 64] = ps4; sw[5 * 64] = ps5; sw[6 * 64] = ps6; sw[7 * 64] = ps7;
    sw[8 * 64] = pq0; sw[9 * 64] = pq1; sw[10 * 64] = pq2; sw[11 * 64] = pq3;
    sw[12 * 64] = pq4; sw[13 * 64] = pq5; sw[14 * 64] = pq6; sw[15 * 64] = pq7;
    __syncthreads();

    // cross-wave reduce + one atomic per entry (1024 entries / 256 threads)
    int part = (blockIdx.x & 31) * 512;
    #pragma unroll
    for (int k = 0; k < 4; ++k) {
        int idx = tid + k * 256;                 // 0..1023
        float s = s_bn[idx] + s_bn[1024 + idx] + s_bn[2048 + idx] + s_bn[3072 + idx];
        int v = idx >> 6, ln = idx & 63;
        int col = ((v & 7) >> 1) * 128 + 2 * ln + (v & 1);
        if (v < 8) atomicAdd(&bn_psum[part + col], s);
        else       atomicAdd(&bn_psq[part + col], s);
    }
}

__global__ __launch_bounds__(256) void k_bnfin(const float* __restrict__ bn_psum,
    const float* __restrict__ bn_psq, const float* __restrict__ bng,
    const float* __restrict__ bnbeta, float* __restrict__ bns, float* __restrict__ bnbv)
{
    int c = blockIdx.x * 256 + threadIdx.x;
    if (c >= 512) return;
    float s = 0.f, q = 0.f;
    #pragma unroll 8
    for (int p = 0; p < 32; ++p) {
        s += bn_psum[p * 512 + c];
        q += bn_psq[p * 512 + c];
    }
    float mean = s * (1.f / NN);
    float var = q * (1.f / NN) - mean * mean;
    float sc = bng[c] / sqrtf(var + 1e-5f);
    bns[c] = sc;
    bnbv[c] = bnbeta[c] - mean * sc;
}

// ---------------- final fused MFMA: 8 waves, col-eighth per wave ------------
// Same 32-node tile + uint4 staging; 512 threads = 8 waves (was 4). Wave w
// owns 2 row-tiles x 2 GEMM1 j-tiles (cols [w*32,+32)) and 1 GEMM2 j-tile
// (cols [w*16,+16)). LDS ~35.6KB -> 4 blocks/CU unchanged, but now 32
// waves/CU cap (was 16) — doubles latency hiding for this latency-bound
// kernel. acc1 halves to 16 VGPR; launch_bounds(512,8) caps VGPR at 64.
__global__ __launch_bounds__(512, 8) void k_final(
    const unsigned int* __restrict__ aggb,
    const float* __restrict__ bns, const float* __restrict__ bnb,
    const unsigned short* __restrict__ w1p, const float* __restrict__ b1,
    const float* __restrict__ lng, const float* __restrict__ lnb,
    const unsigned short* __restrict__ w2p, const float* __restrict__ b2,
    float* __restrict__ out)
{
    __shared__ unsigned int s_z[32 * 260];   // 33280 B; t matrix aliases below
    __shared__ float s_lng[256], s_lnb[256];
    __shared__ float s_ps[8][32], s_pq[8][32];
    __shared__ float s_mu[32], s_iv[32];
    unsigned short* s_ts = reinterpret_cast<unsigned short*>(s_z);  // [32][264]

    const int tid = threadIdx.x;
    const int w = tid >> 6, lane = tid & 63, l15 = lane & 15, g = lane >> 4;
    const int n0 = blockIdx.x * 32;

    if (tid < 256) {
        s_lng[tid] = lng[tid];
        s_lnb[tid] = lnb[tid];
    }

    // stage z = bf16(relu(agg*scale+shift)); uint4: thread owns ucols 4t..4t+3
    // of rows i*8 + (tid>>6), i<4
    const int t6 = tid & 63, r0 = tid >> 6;
    f32x4 sva = *reinterpret_cast<const f32x4*>(bns + 8 * t6);
    f32x4 svb = *reinterpret_cast<const f32x4*>(bns + 8 * t6 + 4);
    f32x4 bva = *reinterpret_cast<const f32x4*>(bnb + 8 * t6);
    f32x4 bvb = *reinterpret_cast<const f32x4*>(bnb + 8 * t6 + 4);
    #pragma unroll
    for (int i = 0; i < 4; ++i) {
        int row = i * 8 + r0;
        int ar = (n0 + row < NN) ? n0 + row : NN - 1;
        uint4 u = *reinterpret_cast<const uint4*>(aggb + (size_t)ar * 256 + t6 * 4);
        uint4 o;
        o.x = pack2(fmaxf(fmaf(bf_lo(u.x), sva[0], bva[0]), 0.f),
                    fmaxf(fmaf(bf_hi(u.x), sva[1], bva[1]), 0.f));
        o.y = pack2(fmaxf(fmaf(bf_lo(u.y), sva[2], bva[2]), 0.f),
                    fmaxf(fmaf(bf_hi(u.y), sva[3], bva[3]), 0.f));
        o.z = pack2(fmaxf(fmaf(bf_lo(u.z), svb[0], bvb[0]), 0.f),
                    fmaxf(fmaf(bf_hi(u.z), svb[1], bvb[1]), 0.f));
        o.w = pack2(fmaxf(fmaf(bf_lo(u.w), svb[2], bvb[2]), 0.f),
                    fmaxf(fmaf(bf_hi(u.w), svb[3], bvb[3]), 0.f));
        *reinterpret_cast<uint4*>(&s_z[row * 260 + t6 * 4]) = o;
    }
    __syncthreads();

    // ---------------- GEMM1: 2 row-tiles x 2 j-tiles, B block-unique --------
    const int4* B1 = reinterpret_cast<const int4*>(w1p);
    f32x4 acc1[4];                           // [rt*2 + j]
    #pragma unroll
    for (int i = 0; i < 4; ++i) acc1[i] = (f32x4){0.f, 0.f, 0.f, 0.f};

    #pragma unroll 2
    for (int kk = 0; kk < 16; ++kk) {
        Frag16B b[2];
        #pragma unroll
        for (int j = 0; j < 2; ++j)
            b[j].i = B1[(kk * 16 + w * 2 + j) * 64 + lane];
        Frag16B a[2];
        #pragma unroll
        for (int rt = 0; rt < 2; ++rt)
            a[rt].i = *reinterpret_cast<const int4*>(
                &s_z[(rt * 16 + l15) * 260 + kk * 16 + g * 4]);
        #pragma unroll
        for (int rt = 0; rt < 2; ++rt)
            #pragma unroll
            for (int j = 0; j < 2; ++j)
                acc1[rt * 2 + j] = __builtin_amdgcn_mfma_f32_16x16x32_bf16(
                    a[rt].s, b[j].s, acc1[rt * 2 + j], 0, 0, 0);
    }
    __syncthreads();   // all z reads done before t overwrites the buffer

    // ---------------- bias + t stash + LN partials (per col-eighth) ---------
    float b1v[2];
    #pragma unroll
    for (int j = 0; j < 2; ++j) b1v[j] = b1[(w * 2 + j) * 16 + l15];

    float ssum[8], ssq[8];                   // [rt*4 + r]
    #pragma unroll
    for (int i = 0; i < 8; ++i) { ssum[i] = 0.f; ssq[i] = 0.f; }
    #pragma unroll
    for (int rt = 0; rt < 2; ++rt)
        #pragma unroll
        for (int j = 0; j < 2; ++j) {
            float bvv = b1v[j];
            #pragma unroll
            for (int r = 0; r < 4; ++r) {
                float tv = acc1[rt * 2 + j][r] + bvv;
                ssum[rt * 4 + r] += tv;
                ssq[rt * 4 + r] = fmaf(tv, tv, ssq[rt * 4 + r]);
                s_ts[(rt * 16 + g * 4 + r) * 264 + (w * 2 + j) * 16 + l15] = f2bf(tv);
            }
        }
    #pragma unroll
    for (int m = 1; m < 16; m <<= 1) {
        #pragma unroll
        for (int i = 0; i < 8; ++i) {
            ssum[i] += __shfl_xor(ssum[i], m);
            ssq[i]  += __shfl_xor(ssq[i], m);
        }
    }
    if (l15 == 0) {
        #pragma unroll
        for (int rt = 0; rt < 2; ++rt)
            #pragma unroll
            for (int r = 0; r < 4; ++r) {
                s_ps[w][rt * 16 + g * 4 + r] = ssum[rt * 4 + r];
                s_pq[w][rt * 16 + g * 4 + r] = ssq[rt * 4 + r];
            }
    }
    __syncthreads();

    if (tid < 32) {
        float s = 0.f, q = 0.f;
        #pragma unroll
        for (int p = 0; p < 8; ++p) { s += s_ps[p][tid]; q += s_pq[p][tid]; }
        float mean = s * (1.f / 256.f);
        float var = q * (1.f / 256.f) - mean * mean;
        s_mu[tid] = mean;
        s_iv[tid] = 1.f / sqrtf(var + 1e-5f);
    }
    __syncthreads();

    // ---------------- GEMM2: K=256 over t; 2 row-tiles x 1 j-tile -----------
    float mu_m[2], iv_m[2];
    #pragma unroll
    for (int rt = 0; rt < 2; ++rt) {
        mu_m[rt] = s_mu[rt * 16 + l15];
        iv_m[rt] = s_iv[rt * 16 + l15];
    }
    const int4* B2 = reinterpret_cast<const int4*>(w2p);

    f32x4 acc2[2];                           // [rt]
    #pragma unroll
    for (int i = 0; i < 2; ++i) acc2[i] = (f32x4){0.f, 0.f, 0.f, 0.f};

    #pragma unroll 2
    for (int kk = 0; kk < 8; ++kk) {
        const int kb = kk * 32 + g * 8;
        Frag16B b;
        b.i = B2[(kk * 8 + w) * 64 + lane];
        float lg[8], lb[8];
        #pragma unroll
        for (int jj = 0; jj < 8; ++jj) { lg[jj] = s_lng[kb + jj]; lb[jj] = s_lnb[kb + jj]; }
        #pragma unroll
        for (int rt = 0; rt < 2; ++rt) {
            int4 traw = *reinterpret_cast<const int4*>(
                &s_ts[(rt * 16 + l15) * 264 + kb]);
            const unsigned short* tu = reinterpret_cast<const unsigned short*>(&traw);
            short8 af;
            #pragma unroll
            for (int jj = 0; jj < 8; ++jj) {
                float tv = __uint_as_float(((unsigned int)tu[jj]) << 16);
                float rn = fmaxf(fmaf((tv - mu_m[rt]) * iv_m[rt], lg[jj], lb[jj]), 0.f);
                af[jj] = (short)f2bf(rn);
            }
            acc2[rt] = __builtin_amdgcn_mfma_f32_16x16x32_bf16(
                af, b.s, acc2[rt], 0, 0, 0);
        }
    }

    float b2v = b2[w * 16 + l15];

    #pragma unroll
    for (int rt = 0; rt < 2; ++rt)
        #pragma unroll
        for (int r = 0; r < 4; ++r) {
            int n = n0 + rt * 16 + g * 4 + r;
            if (n < NN)
                out[(size_t)n * 128 + w * 16 + l15] = acc2[rt][r] + b2v;
        }
}

// ---------------------------------------------------------------------------
extern "C" void kernel_launch(void* const* d_in, const int* in_sizes, int n_in,
                              void* d_out, int out_size, void* d_ws, size_t ws_size,
                              hipStream_t stream)
{
    const float* x    = (const float*)d_in[0];
    const int*   ei   = (const int*)d_in[1];
    const float* pos  = (const float*)d_in[2];
    const float* wft  = (const float*)d_in[3];
    const float* bft  = (const float*)d_in[4];
    const float* wcv  = (const float*)d_in[5];
    const float* bcv  = (const float*)d_in[6];
    const float* vfp  = (const float*)d_in[7];
    const float* vpar = (const float*)d_in[8];
    const float* bng  = (const float*)d_in[9];
    const float* bnbe = (const float*)d_in[10];
    const float* att  = (const float*)d_in[11];
    const float* w1   = (const float*)d_in[12];
    const float* b1   = (const float*)d_in[13];
    const float* lng  = (const float*)d_in[14];
    const float* lnb  = (const float*)d_in[15];
    const float* w2   = (const float*)d_in[16];
    const float* b2   = (const float*)d_in[17];
    float* out = (float*)d_out;

    float* ws = (float*)d_ws;
    size_t off = 0;
    unsigned int* msg  = (unsigned int*)(ws + off); off += (size_t)NN * 64;    // bf16 [N][128]
    unsigned int* aggb = (unsigned int*)(ws + off); off += (size_t)NN * 256;   // bf16 [N][512]
    unsigned short* w1p  = (unsigned short*)(ws + off); off += 65536;
    unsigned short* w2p  = (unsigned short*)(ws + off); off += 16384;
    unsigned short* wftp = (unsigned short*)(ws + off); off += 8192;
    unsigned short* wcvp = (unsigned short*)(ws + off); off += 8192;
    float4* pos4 = (float4*)(ws + off); off += (size_t)NN * 4;
    float* bns  = ws + off; off += 512;
    float* bnbv = ws + off; off += 512;
    uint4* csre = (uint4*)(ws + off); off += (size_t)EE * 4;    // AoS: {src, ab01, ab23, pad}
    int* rank   = (int*)(ws + off); off += (size_t)EE;          // per-edge CSR rank
    int* offs   = (int*)(ws + off); off += NN + 4;
    int* loc    = (int*)(ws + off); off += NN;
    int* bsum   = (int*)(ws + off); off += 256;
    float* blockmax = ws + off; off += 3136;
    float* dmax = ws + off; off += 4;
    float* bn_psum = ws + off; off += 32 * 512;
    float* bn_psq  = ws + off; off += 32 * 512;
    int* counts = (int*)(ws + off); off += NN;

    k_prep<<<196, 256, 0, stream>>>(w1, att, w2, wft, wcv, pos, w1p, w2p, wftp, wcvp,
                                    pos4, counts, bn_psum, bn_psq);
    k_ft_conv<<<782, 256, 0, stream>>>(x, wftp, bft, wcvp, bcv, msg);
    k_edge_pass1<<<3125, 256, 0, stream>>>(ei, pos4, blockmax, counts, rank);
    k_scan1<<<196, 256, 0, stream>>>(counts, loc, bsum);
    k_scan3<<<197, 256, 0, stream>>>(loc, bsum, blockmax, offs, dmax, 3125);
    k_fill<<<3125, 256, 0, stream>>>(ei, pos4, dmax, vfp, vpar, offs, rank, csre);
    k_agg<<<2048, 256, 0, stream>>>(offs, csre, msg, aggb, bn_psum, bn_psq);
    k_bnfin<<<2, 256, 0, stream>>>(bn_psum, bn_psq, bng, bnbe, bns, bnbv);
    k_final<<<1563, 512, 0, stream>>>(aggb, bns, bnbv, w1p, b1, lng, lnb, w2p, b2, out);
}

// Round 16
// 270.841 us; speedup vs baseline: 1.0551x; 1.0551x over previous
//
#include <hip/hip_runtime.h>
#include <hip/hip_bf16.h>

#define NN 50000
#define EE 800000

typedef short short8 __attribute__((ext_vector_type(8)));
typedef float f32x4 __attribute__((ext_vector_type(4)));

union Frag16B { short8 s; int4 i; };
union H4 { _Float16 h[4]; uint2 u; };

static __device__ __forceinline__ unsigned short f2bf(float f) {
    union { float f; unsigned u; } v; v.f = f;
    unsigned r = v.u + 0x7FFF + ((v.u >> 16) & 1);   // RNE
    return (unsigned short)(r >> 16);
}
static __device__ __forceinline__ float bf_lo(unsigned int u) {
    return __uint_as_float(u << 16);
}
static __device__ __forceinline__ float bf_hi(unsigned int u) {
    return __uint_as_float(u & 0xFFFF0000u);
}
static __device__ __forceinline__ unsigned int pack2(float a, float b) {
    return (unsigned int)f2bf(a) | ((unsigned int)f2bf(b) << 16);
}

// ---------------- prep: weight packing + pos->float4 + workspace zeroing ----
__global__ __launch_bounds__(256) void k_prep(
    const float* __restrict__ w1,  const float* __restrict__ att,
    const float* __restrict__ w2,
    const float* __restrict__ wft, const float* __restrict__ wcv,
    const float* __restrict__ pos,
    unsigned short* __restrict__ w1p, unsigned short* __restrict__ w2p,
    unsigned short* __restrict__ wftp, unsigned short* __restrict__ wcvp,
    float4* __restrict__ pos4,
    int* __restrict__ counts, float* __restrict__ bn_psum, float* __restrict__ bn_psq)
{
    int gth = blockIdx.x * 256 + threadIdx.x;
    int lane = gth & 63, l15 = lane & 15, gg = lane >> 4;
    if (gth < 16384) {                       // w1p: kk<16, t<16, fold att[col]
        int t = (gth >> 6) & 15, kk = gth >> 10;
        int row = t * 16 + l15, c0 = kk * 32 + gg * 8;
        unsigned int pk[4];
        #pragma unroll
        for (int j = 0; j < 4; ++j) {
            int c = c0 + 2 * j;
            pk[j] = pack2(w1[row * 512 + c] * att[c],
                          w1[row * 512 + c + 1] * att[c + 1]);
        }
        *reinterpret_cast<uint4*>(w1p + (size_t)gth * 8) = make_uint4(pk[0], pk[1], pk[2], pk[3]);
        bn_psum[gth] = 0.f;
        bn_psq[gth] = 0.f;
    }
    if (gth < 4096) {                        // w2p: kk<8, t<8
        int t = (gth >> 6) & 7, kk = gth >> 9;
        int row = t * 16 + l15, c0 = kk * 32 + gg * 8;
        unsigned int pk[4];
        #pragma unroll
        for (int j = 0; j < 4; ++j) {
            int c = c0 + 2 * j;
            pk[j] = pack2(w2[row * 256 + c], w2[row * 256 + c + 1]);
        }
        *reinterpret_cast<uint4*>(w2p + (size_t)gth * 8) = make_uint4(pk[0], pk[1], pk[2], pk[3]);
    }
    if (gth < 2048) {                        // wftp / wcvp: kk<4, t<8
        int t = (gth >> 6) & 7, kk = gth >> 9;
        int row = t * 16 + l15, c0 = kk * 32 + gg * 8;
        unsigned int pa[4], pb[4];
        #pragma unroll
        for (int j = 0; j < 4; ++j) {
            int c = c0 + 2 * j;
            pa[j] = pack2(wft[row * 128 + c], wft[row * 128 + c + 1]);
            pb[j] = pack2(wcv[row * 128 + c], wcv[row * 128 + c + 1]);
        }
        *reinterpret_cast<uint4*>(wftp + (size_t)gth * 8) = make_uint4(pa[0], pa[1], pa[2], pa[3]);
        *reinterpret_cast<uint4*>(wcvp + (size_t)gth * 8) = make_uint4(pb[0], pb[1], pb[2], pb[3]);
    }
    if (gth < NN) {                          // pos -> padded float4; zero counts
        pos4[gth] = make_float4(pos[gth * 3 + 0], pos[gth * 3 + 1], pos[gth * 3 + 2], 0.f);
        counts[gth] = 0;
    }
}

// ---------------- fused node GEMMs (MFMA): msg = (relu(x WftT+bft)) WcvT + bcv
// Col-split remap (R12): wave w owns ALL 64 rows x its col-quarter.
__global__ __launch_bounds__(256) void k_ft_conv(
    const float* __restrict__ x,
    const unsigned short* __restrict__ wftp, const float* __restrict__ bft,
    const unsigned short* __restrict__ wcvp, const float* __restrict__ bcv,
    unsigned int* __restrict__ msg)          // bf16 [NN][128] as uint[NN][64]
{
    __shared__ unsigned int s_x[64 * 68];    // bf16 tile (reused for out)
    __shared__ unsigned short s_h[64 * 136];
    const int tid = threadIdx.x;
    const int w = tid >> 6, lane = tid & 63, l15 = lane & 15, g = lane >> 4;
    const int n0 = blockIdx.x * 64;

    #pragma unroll
    for (int i = 0; i < 8; ++i) {
        int lin = tid + i * 256;
        int row = lin >> 5, c4 = lin & 31;
        int ar = (n0 + row < NN) ? n0 + row : NN - 1;
        float4 v = *reinterpret_cast<const float4*>(x + (size_t)ar * 128 + c4 * 4);
        s_x[row * 68 + c4 * 2]     = pack2(v.x, v.y);
        s_x[row * 68 + c4 * 2 + 1] = pack2(v.z, v.w);
    }
    __syncthreads();

    float bftv[2], bcvv[2];
    #pragma unroll
    for (int t = 0; t < 2; ++t) {
        bftv[t] = bft[(w * 2 + t) * 16 + l15];
        bcvv[t] = bcv[(w * 2 + t) * 16 + l15];
    }

    const int4* Bf = reinterpret_cast<const int4*>(wftp);
    f32x4 acc[8];                            // [rt*2 + t]
    #pragma unroll
    for (int i = 0; i < 8; ++i) acc[i] = (f32x4){0.f, 0.f, 0.f, 0.f};
    #pragma unroll
    for (int kk = 0; kk < 4; ++kk) {
        Frag16B b[2];
        #pragma unroll
        for (int t = 0; t < 2; ++t)
            b[t].i = Bf[(kk * 8 + w * 2 + t) * 64 + lane];
        Frag16B a[4];
        #pragma unroll
        for (int rt = 0; rt < 4; ++rt)
            a[rt].i = *reinterpret_cast<const int4*>(
                &s_x[(rt * 16 + l15) * 68 + kk * 16 + g * 4]);
        #pragma unroll
        for (int rt = 0; rt < 4; ++rt)
            #pragma unroll
            for (int t = 0; t < 2; ++t)
                acc[rt * 2 + t] = __builtin_amdgcn_mfma_f32_16x16x32_bf16(
                    a[rt].s, b[t].s, acc[rt * 2 + t], 0, 0, 0);
    }
    #pragma unroll
    for (int rt = 0; rt < 4; ++rt)
        #pragma unroll
        for (int t = 0; t < 2; ++t)
            #pragma unroll
            for (int r = 0; r < 4; ++r)
                s_h[(rt * 16 + g * 4 + r) * 136 + (w * 2 + t) * 16 + l15] =
                    f2bf(fmaxf(acc[rt * 2 + t][r] + bftv[t], 0.f));
    __syncthreads();

    const int4* Bc = reinterpret_cast<const int4*>(wcvp);
    #pragma unroll
    for (int i = 0; i < 8; ++i) acc[i] = (f32x4){0.f, 0.f, 0.f, 0.f};
    #pragma unroll
    for (int kk = 0; kk < 4; ++kk) {
        Frag16B b[2];
        #pragma unroll
        for (int t = 0; t < 2; ++t)
            b[t].i = Bc[(kk * 8 + w * 2 + t) * 64 + lane];
        Frag16B a[4];
        #pragma unroll
        for (int rt = 0; rt < 4; ++rt)
            a[rt].i = *reinterpret_cast<const int4*>(
                &s_h[(rt * 16 + l15) * 136 + kk * 32 + g * 8]);
        #pragma unroll
        for (int rt = 0; rt < 4; ++rt)
            #pragma unroll
            for (int t = 0; t < 2; ++t)
                acc[rt * 2 + t] = __builtin_amdgcn_mfma_f32_16x16x32_bf16(
                    a[rt].s, b[t].s, acc[rt * 2 + t], 0, 0, 0);
    }
    unsigned short* s_o = reinterpret_cast<unsigned short*>(s_x);
    #pragma unroll
    for (int rt = 0; rt < 4; ++rt)
        #pragma unroll
        for (int t = 0; t < 2; ++t)
            #pragma unroll
            for (int r = 0; r < 4; ++r)
                s_o[(rt * 16 + g * 4 + r) * 136 + (w * 2 + t) * 16 + l15] =
                    f2bf(acc[rt * 2 + t][r] + bcvv[t]);
    __syncthreads();
    #pragma unroll
    for (int i = 0; i < 8; ++i) {
        int lin = tid + i * 256;
        int row = lin >> 5, cu2 = lin & 31;
        if (n0 + row < NN) {
            uint2 v;
            v.x = s_x[row * 68 + cu2 * 2];
            v.y = s_x[row * 68 + cu2 * 2 + 1];
            *reinterpret_cast<uint2*>(msg + (size_t)(n0 + row) * 64 + cu2 * 2) = v;
        }
    }
}

// ---------------- edge pass 1: degree + rank capture + block max ------------
__global__ __launch_bounds__(256) void k_edge_pass1(
    const int* __restrict__ ei, const float4* __restrict__ pos4,
    float* __restrict__ blockmax, int* __restrict__ counts,
    int* __restrict__ rank)
{
    __shared__ float smax[4];
    int e = blockIdx.x * 256 + threadIdx.x;       // grid covers EE exactly
    int s = ei[e], d = ei[EE + e];
    float4 ps = pos4[s], pd = pos4[d];
    float dx = ps.x - pd.x, dy = ps.y - pd.y, dz = ps.z - pd.z;
    float dist = sqrtf(dx * dx + dy * dy + dz * dz);
    rank[e] = atomicAdd(&counts[d], 1);

    float m = dist;
    #pragma unroll
    for (int o = 32; o >= 1; o >>= 1)
        m = fmaxf(m, __shfl_xor(m, o));
    if ((threadIdx.x & 63) == 0) smax[threadIdx.x >> 6] = m;
    __syncthreads();
    if (threadIdx.x == 0)
        blockmax[blockIdx.x] = fmaxf(fmaxf(smax[0], smax[1]), fmaxf(smax[2], smax[3]));
}

// ---------------- scan 1: per-block inclusive scan of counts ----------------
__global__ __launch_bounds__(256) void k_scan1(const int* __restrict__ counts,
    int* __restrict__ loc, int* __restrict__ bsum)
{
    __shared__ int sd[256];
    int i = blockIdx.x * 256 + threadIdx.x;
    int v = (i < NN) ? counts[i] : 0;
    sd[threadIdx.x] = v;
    __syncthreads();
    for (int ofs = 1; ofs < 256; ofs <<= 1) {
        int t = (threadIdx.x >= ofs) ? sd[threadIdx.x - ofs] : 0;
        __syncthreads();
        sd[threadIdx.x] += t;
        __syncthreads();
    }
    int incl = sd[threadIdx.x];
    if (i < NN) loc[i] = incl - v;
    if (threadIdx.x == 255) bsum[blockIdx.x] = incl;
}

// ---------------- scan 2 (merged): offs with inline bofs + dmax block -------
__global__ __launch_bounds__(256) void k_scan3(const int* __restrict__ loc,
    const int* __restrict__ bsum, const float* __restrict__ blockmax,
    int* __restrict__ offs, float* __restrict__ dmax, int nmb)
{
    if (blockIdx.x < 196) {
        __shared__ int sd[256];
        __shared__ int s_v[256];
        int v = (threadIdx.x < 196) ? bsum[threadIdx.x] : 0;
        sd[threadIdx.x] = v;
        s_v[threadIdx.x] = v;
        __syncthreads();
        for (int ofs = 1; ofs < 256; ofs <<= 1) {
            int t = (threadIdx.x >= ofs) ? sd[threadIdx.x - ofs] : 0;
            __syncthreads();
            sd[threadIdx.x] += t;
            __syncthreads();
        }
        int bofs = sd[blockIdx.x] - s_v[blockIdx.x];   // exclusive prefix at this block
        int i = blockIdx.x * 256 + threadIdx.x;
        if (i < NN) offs[i] = loc[i] + bofs;
        if (i == 0) offs[NN] = EE;
    } else {
        __shared__ float smax[4];
        float m = 0.f;
        for (int i = threadIdx.x; i < nmb; i += 256) m = fmaxf(m, blockmax[i]);
        #pragma unroll
        for (int o = 32; o >= 1; o >>= 1)
            m = fmaxf(m, __shfl_xor(m, o));
        if ((threadIdx.x & 63) == 0) smax[threadIdx.x >> 6] = m;
        __syncthreads();
        if (threadIdx.x == 0)
            dmax[0] = fmaxf(fmaxf(smax[0], smax[1]), fmaxf(smax[2], smax[3]));
    }
}

// ---------------- edge pass 2: geometry + ab + AoS CSR record ---------------
__global__ __launch_bounds__(256) void k_fill(
    const int* __restrict__ ei, const float4* __restrict__ pos4,
    const float* __restrict__ dmaxp,
    const float* __restrict__ vfp, const float* __restrict__ vpar,
    const int* __restrict__ offs, const int* __restrict__ rank,
    uint4* __restrict__ csre)
{
    int e = blockIdx.x * 256 + threadIdx.x;       // grid covers EE exactly
    int s = ei[e], d = ei[EE + e];
    float4 ps = pos4[s], pd = pos4[d];
    float dx = ps.x - pd.x, dy = ps.y - pd.y, dz = ps.z - pd.z;
    float dist = sqrtf(dx * dx + dy * dy + dz * dz);
    float rinv = 1.f / (dist + 1e-8f);
    float dsum = (dx + dy + dz) * rinv;
    float r = dist / dmaxp[0];
    float vf = vfp[0];
    H4 p;
    #pragma unroll
    for (int k = 0; k < 4; ++k) {
        float v = vf * fminf(r, vpar[k]);
        p.h[k] = (_Float16)(sqrtf(1.f - v * v + 1e-8f) / (1.f + v * dsum));
    }
    int slot = offs[d] + rank[e];
    csre[slot] = make_uint4((unsigned)s, p.u.x, p.u.y, 0u);
}

// ---------------- aggregation + fused BN partial stats ----------------------
// R8 structure (locally converged). AoS csre records, wave-uniform indices.
__global__ __launch_bounds__(256) void k_agg(
    const int* __restrict__ offs, const uint4* __restrict__ csre,
    const unsigned int* __restrict__ msg,
    unsigned int* __restrict__ aggb,         // bf16 [NN][512] as uint[NN][256]
    float* __restrict__ bn_psum, float* __restrict__ bn_psq)
{
    __shared__ float s_bn[4 * 1024];         // [wave][16 vals][64 lanes]
    const int tid = threadIdx.x;
    const int lane = tid & 63;
    const int w = __builtin_amdgcn_readfirstlane(tid >> 6);
    const int gw = (blockIdx.x << 2) | w;    // 0..8191

    float ps0 = 0, ps1 = 0, ps2 = 0, ps3 = 0, ps4 = 0, ps5 = 0, ps6 = 0, ps7 = 0;
    float pq0 = 0, pq1 = 0, pq2 = 0, pq3 = 0, pq4 = 0, pq5 = 0, pq6 = 0, pq7 = 0;

    for (int n = gw; n < NN; n += 8192) {
        int st = __builtin_amdgcn_readfirstlane(offs[n]);
        int en = __builtin_amdgcn_readfirstlane(offs[n + 1]);
        float a00 = 0, a10 = 0, a20 = 0, a30 = 0, a01 = 0, a11 = 0, a21 = 0, a31 = 0;

        for (int e = st; e < en; e += 8) {
            int idx[8];
            uint4 rr[8];
            unsigned int uu[8];
            #pragma unroll
            for (int j = 0; j < 8; ++j) {
                int ee = e + j;
                idx[j] = (ee < en) ? ee : en - 1;       // wave-uniform clamp
            }
            #pragma unroll
            for (int j = 0; j < 8; ++j) rr[j] = csre[idx[j]];
            #pragma unroll
            for (int j = 0; j < 8; ++j)
                uu[j] = msg[(size_t)rr[j].x * 64 + lane];
            #pragma unroll
            for (int j = 0; j < 8; ++j) {
                bool valid = (e + j) < en;              // wave-uniform
                H4 p;
                p.u.x = valid ? rr[j].y : 0u;
                p.u.y = valid ? rr[j].z : 0u;
                float m0 = bf_lo(uu[j]), m1 = bf_hi(uu[j]);
                a00 = fmaf((float)p.h[0], m0, a00); a01 = fmaf((float)p.h[0], m1, a01);
                a10 = fmaf((float)p.h[1], m0, a10); a11 = fmaf((float)p.h[1], m1, a11);
                a20 = fmaf((float)p.h[2], m0, a20); a21 = fmaf((float)p.h[2], m1, a21);
                a30 = fmaf((float)p.h[3], m0, a30); a31 = fmaf((float)p.h[3], m1, a31);
            }
        }

        unsigned int* o = aggb + (size_t)n * 256 + lane;   // col c = k*128 + h
        o[0]   = pack2(a00, a01);
        o[64]  = pack2(a10, a11);
        o[128] = pack2(a20, a21);
        o[192] = pack2(a30, a31);

        ps0 += a00; pq0 = fmaf(a00, a00, pq0);
        ps1 += a01; pq1 = fmaf(a01, a01, pq1);
        ps2 += a10; pq2 = fmaf(a10, a10, pq2);
        ps3 += a11; pq3 = fmaf(a11, a11, pq3);
        ps4 += a20; pq4 = fmaf(a20, a20, pq4);
        ps5 += a21; pq5 = fmaf(a21, a21, pq5);
        ps6 += a30; pq6 = fmaf(a30, a30, pq6);
        ps7 += a31; pq7 = fmaf(a31, a31, pq7);
    }

    // per-wave partials -> LDS
    float* sw = s_bn + w * 1024 + lane;
    sw[0 * 64] = ps0; sw[1 * 64] = ps1; sw[2 * 64] = ps2; sw[3 * 64] = ps3;
    sw[4 * 64] = ps4; sw[5 * 64] = ps5; sw[6 * 64] = ps6; sw[7 * 64] = ps7;
    sw[8 * 64] = pq0; sw[9 * 64] = pq1; sw[10 * 64] = pq2; sw[11 * 64] = pq3;
    sw[12 * 64] = pq4; sw[13 * 64] = pq5; sw[14 * 64] = pq6; sw[15 * 64] = pq7;
    __syncthreads();

    // cross-wave reduce + one atomic per entry (1024 entries / 256 threads)
    int part = (blockIdx.x & 31) * 512;
    #pragma unroll
    for (int k = 0; k < 4; ++k) {
        int idx = tid + k * 256;                 // 0..1023
        float s = s_bn[idx] + s_bn[1024 + idx] + s_bn[2048 + idx] + s_bn[3072 + idx];
        int v = idx >> 6, ln = idx & 63;
        int col = ((v & 7) >> 1) * 128 + 2 * ln + (v & 1);
        if (v < 8) atomicAdd(&bn_psum[part + col], s);
        else       atomicAdd(&bn_psq[part + col], s);
    }
}

__global__ __launch_bounds__(256) void k_bnfin(const float* __restrict__ bn_psum,
    const float* __restrict__ bn_psq, const float* __restrict__ bng,
    const float* __restrict__ bnbeta, float* __restrict__ bns, float* __restrict__ bnbv)
{
    int c = blockIdx.x * 256 + threadIdx.x;
    if (c >= 512) return;
    float s = 0.f, q = 0.f;
    #pragma unroll 8
    for (int p = 0; p < 32; ++p) {
        s += bn_psum[p * 512 + c];
        q += bn_psq[p * 512 + c];
    }
    float mean = s * (1.f / NN);
    float var = q * (1.f / NN) - mean * mean;
    float sc = bng[c] / sqrtf(var + 1e-5f);
    bns[c] = sc;
    bnbv[c] = bnbeta[c] - mean * sc;
}

// ---------------- final fused MFMA: 8 waves; GEMM2 full-sector stores -------
// R15 base (8 waves, 32-node tile, uint4 staging) with GEMM2 remapped:
// wave w -> (rt, jp) = (w>>2, w&3): ONE row-tile x TWO adjacent j-tiles
// (cols [jp*32,+32) = full 128B sector per row) — fixes R15's partial-sector
// RMW (WRITE 25->40.6MB was the regression). B2 frags duplicated x2 across
// wave pairs (+16KB/block, L2-hit). af built once per kk, shared by 2 MFMAs.
__global__ __launch_bounds__(512, 8) void k_final(
    const unsigned int* __restrict__ aggb,
    const float* __restrict__ bns, const float* __restrict__ bnb,
    const unsigned short* __restrict__ w1p, const float* __restrict__ b1,
    const float* __restrict__ lng, const float* __restrict__ lnb,
    const unsigned short* __restrict__ w2p, const float* __restrict__ b2,
    float* __restrict__ out)
{
    __shared__ unsigned int s_z[32 * 260];   // 33280 B; t matrix aliases below
    __shared__ float s_lng[256], s_lnb[256];
    __shared__ float s_ps[8][32], s_pq[8][32];
    __shared__ float s_mu[32], s_iv[32];
    unsigned short* s_ts = reinterpret_cast<unsigned short*>(s_z);  // [32][264]

    const int tid = threadIdx.x;
    const int w = tid >> 6, lane = tid & 63, l15 = lane & 15, g = lane >> 4;
    const int n0 = blockIdx.x * 32;

    if (tid < 256) {
        s_lng[tid] = lng[tid];
        s_lnb[tid] = lnb[tid];
    }

    // stage z = bf16(relu(agg*scale+shift)); uint4: thread owns ucols 4t..4t+3
    // of rows i*8 + (tid>>6), i<4
    const int t6 = tid & 63, r0 = tid >> 6;
    f32x4 sva = *reinterpret_cast<const f32x4*>(bns + 8 * t6);
    f32x4 svb = *reinterpret_cast<const f32x4*>(bns + 8 * t6 + 4);
    f32x4 bva = *reinterpret_cast<const f32x4*>(bnb + 8 * t6);
    f32x4 bvb = *reinterpret_cast<const f32x4*>(bnb + 8 * t6 + 4);
    #pragma unroll
    for (int i = 0; i < 4; ++i) {
        int row = i * 8 + r0;
        int ar = (n0 + row < NN) ? n0 + row : NN - 1;
        uint4 u = *reinterpret_cast<const uint4*>(aggb + (size_t)ar * 256 + t6 * 4);
        uint4 o;
        o.x = pack2(fmaxf(fmaf(bf_lo(u.x), sva[0], bva[0]), 0.f),
                    fmaxf(fmaf(bf_hi(u.x), sva[1], bva[1]), 0.f));
        o.y = pack2(fmaxf(fmaf(bf_lo(u.y), sva[2], bva[2]), 0.f),
                    fmaxf(fmaf(bf_hi(u.y), sva[3], bva[3]), 0.f));
        o.z = pack2(fmaxf(fmaf(bf_lo(u.z), svb[0], bvb[0]), 0.f),
                    fmaxf(fmaf(bf_hi(u.z), svb[1], bvb[1]), 0.f));
        o.w = pack2(fmaxf(fmaf(bf_lo(u.w), svb[2], bvb[2]), 0.f),
                    fmaxf(fmaf(bf_hi(u.w), svb[3], bvb[3]), 0.f));
        *reinterpret_cast<uint4*>(&s_z[row * 260 + t6 * 4]) = o;
    }
    __syncthreads();

    // ---------------- GEMM1: 2 row-tiles x 2 j-tiles, B block-unique --------
    const int4* B1 = reinterpret_cast<const int4*>(w1p);
    f32x4 acc1[4];                           // [rt*2 + j]
    #pragma unroll
    for (int i = 0; i < 4; ++i) acc1[i] = (f32x4){0.f, 0.f, 0.f, 0.f};

    #pragma unroll 2
    for (int kk = 0; kk < 16; ++kk) {
        Frag16B b[2];
        #pragma unroll
        for (int j = 0; j < 2; ++j)
            b[j].i = B1[(kk * 16 + w * 2 + j) * 64 + lane];
        Frag16B a[2];
        #pragma unroll
        for (int rt = 0; rt < 2; ++rt)
            a[rt].i = *reinterpret_cast<const int4*>(
                &s_z[(rt * 16 + l15) * 260 + kk * 16 + g * 4]);
        #pragma unroll
        for (int rt = 0; rt < 2; ++rt)
            #pragma unroll
            for (int j = 0; j < 2; ++j)
                acc1[rt * 2 + j] = __builtin_amdgcn_mfma_f32_16x16x32_bf16(
                    a[rt].s, b[j].s, acc1[rt * 2 + j], 0, 0, 0);
    }
    __syncthreads();   // all z reads done before t overwrites the buffer

    // ---------------- bias + t stash + LN partials (per col-eighth) ---------
    float b1v[2];
    #pragma unroll
    for (int j = 0; j < 2; ++j) b1v[j] = b1[(w * 2 + j) * 16 + l15];

    float ssum[8], ssq[8];                   // [rt*4 + r]
    #pragma unroll
    for (int i = 0; i < 8; ++i) { ssum[i] = 0.f; ssq[i] = 0.f; }
    #pragma unroll
    for (int rt = 0; rt < 2; ++rt)
        #pragma unroll
        for (int j = 0; j < 2; ++j) {
            float bvv = b1v[j];
            #pragma unroll
            for (int r = 0; r < 4; ++r) {
                float tv = acc1[rt * 2 + j][r] + bvv;
                ssum[rt * 4 + r] += tv;
                ssq[rt * 4 + r] = fmaf(tv, tv, ssq[rt * 4 + r]);
                s_ts[(rt * 16 + g * 4 + r) * 264 + (w * 2 + j) * 16 + l15] = f2bf(tv);
            }
        }
    #pragma unroll
    for (int m = 1; m < 16; m <<= 1) {
        #pragma unroll
        for (int i = 0; i < 8; ++i) {
            ssum[i] += __shfl_xor(ssum[i], m);
            ssq[i]  += __shfl_xor(ssq[i], m);
        }
    }
    if (l15 == 0) {
        #pragma unroll
        for (int rt = 0; rt < 2; ++rt)
            #pragma unroll
            for (int r = 0; r < 4; ++r) {
                s_ps[w][rt * 16 + g * 4 + r] = ssum[rt * 4 + r];
                s_pq[w][rt * 16 + g * 4 + r] = ssq[rt * 4 + r];
            }
    }
    __syncthreads();

    if (tid < 32) {
        float s = 0.f, q = 0.f;
        #pragma unroll
        for (int p = 0; p < 8; ++p) { s += s_ps[p][tid]; q += s_pq[p][tid]; }
        float mean = s * (1.f / 256.f);
        float var = q * (1.f / 256.f) - mean * mean;
        s_mu[tid] = mean;
        s_iv[tid] = 1.f / sqrtf(var + 1e-5f);
    }
    __syncthreads();

    // ---------------- GEMM2: wave (rt,jp) = (w>>2, w&3); 2 adjacent j-tiles -
    const int rt2 = w >> 2, jp = w & 3;
    const float mu_s = s_mu[rt2 * 16 + l15];
    const float iv_s = s_iv[rt2 * 16 + l15];
    const int4* B2 = reinterpret_cast<const int4*>(w2p);
    const unsigned short* trow = s_ts + (rt2 * 16 + l15) * 264;

    f32x4 acc2[2];                           // [j]
    #pragma unroll
    for (int i = 0; i < 2; ++i) acc2[i] = (f32x4){0.f, 0.f, 0.f, 0.f};

    #pragma unroll 2
    for (int kk = 0; kk < 8; ++kk) {
        const int kb = kk * 32 + g * 8;
        Frag16B b[2];
        #pragma unroll
        for (int j = 0; j < 2; ++j)
            b[j].i = B2[(kk * 8 + jp * 2 + j) * 64 + lane];
        int4 traw = *reinterpret_cast<const int4*>(trow + kb);
        const unsigned short* tu = reinterpret_cast<const unsigned short*>(&traw);
        short8 af;
        #pragma unroll
        for (int jj = 0; jj < 8; ++jj) {
            float tv = __uint_as_float(((unsigned int)tu[jj]) << 16);
            float rn = fmaxf(fmaf((tv - mu_s) * iv_s, s_lng[kb + jj], s_lnb[kb + jj]), 0.f);
            af[jj] = (short)f2bf(rn);
        }
        #pragma unroll
        for (int j = 0; j < 2; ++j)
            acc2[j] = __builtin_amdgcn_mfma_f32_16x16x32_bf16(
                af, b[j].s, acc2[j], 0, 0, 0);
    }

    float b2v[2];
    #pragma unroll
    for (int j = 0; j < 2; ++j) b2v[j] = b2[(jp * 2 + j) * 16 + l15];

    #pragma unroll
    for (int j = 0; j < 2; ++j)
        #pragma unroll
        for (int r = 0; r < 4; ++r) {
            int n = n0 + rt2 * 16 + g * 4 + r;
            if (n < NN)
                out[(size_t)n * 128 + (jp * 2 + j) * 16 + l15] = acc2[j][r] + b2v[j];
        }
}

// ---------------------------------------------------------------------------
extern "C" void kernel_launch(void* const* d_in, const int* in_sizes, int n_in,
                              void* d_out, int out_size, void* d_ws, size_t ws_size,
                              hipStream_t stream)
{
    const float* x    = (const float*)d_in[0];
    const int*   ei   = (const int*)d_in[1];
    const float* pos  = (const float*)d_in[2];
    const float* wft  = (const float*)d_in[3];
    const float* bft  = (const float*)d_in[4];
    const float* wcv  = (const float*)d_in[5];
    const float* bcv  = (const float*)d_in[6];
    const float* vfp  = (const float*)d_in[7];
    const float* vpar = (const float*)d_in[8];
    const float* bng  = (const float*)d_in[9];
    const float* bnbe = (const float*)d_in[10];
    const float* att  = (const float*)d_in[11];
    const float* w1   = (const float*)d_in[12];
    const float* b1   = (const float*)d_in[13];
    const float* lng  = (const float*)d_in[14];
    const float* lnb  = (const float*)d_in[15];
    const float* w2   = (const float*)d_in[16];
    const float* b2   = (const float*)d_in[17];
    float* out = (float*)d_out;

    float* ws = (float*)d_ws;
    size_t off = 0;
    unsigned int* msg  = (unsigned int*)(ws + off); off += (size_t)NN * 64;    // bf16 [N][128]
    unsigned int* aggb = (unsigned int*)(ws + off); off += (size_t)NN * 256;   // bf16 [N][512]
    unsigned short* w1p  = (unsigned short*)(ws + off); off += 65536;
    unsigned short* w2p  = (unsigned short*)(ws + off); off += 16384;
    unsigned short* wftp = (unsigned short*)(ws + off); off += 8192;
    unsigned short* wcvp = (unsigned short*)(ws + off); off += 8192;
    float4* pos4 = (float4*)(ws + off); off += (size_t)NN * 4;
    float* bns  = ws + off; off += 512;
    float* bnbv = ws + off; off += 512;
    uint4* csre = (uint4*)(ws + off); off += (size_t)EE * 4;    // AoS: {src, ab01, ab23, pad}
    int* rank   = (int*)(ws + off); off += (size_t)EE;          // per-edge CSR rank
    int* offs   = (int*)(ws + off); off += NN + 4;
    int* loc    = (int*)(ws + off); off += NN;
    int* bsum   = (int*)(ws + off); off += 256;
    float* blockmax = ws + off; off += 3136;
    float* dmax = ws + off; off += 4;
    float* bn_psum = ws + off; off += 32 * 512;
    float* bn_psq  = ws + off; off += 32 * 512;
    int* counts = (int*)(ws + off); off += NN;

    k_prep<<<196, 256, 0, stream>>>(w1, att, w2, wft, wcv, pos, w1p, w2p, wftp, wcvp,
                                    pos4, counts, bn_psum, bn_psq);
    k_ft_conv<<<782, 256, 0, stream>>>(x, wftp, bft, wcvp, bcv, msg);
    k_edge_pass1<<<3125, 256, 0, stream>>>(ei, pos4, blockmax, counts, rank);
    k_scan1<<<196, 256, 0, stream>>>(counts, loc, bsum);
    k_scan3<<<197, 256, 0, stream>>>(loc, bsum, blockmax, offs, dmax, 3125);
    k_fill<<<3125, 256, 0, stream>>>(ei, pos4, dmax, vfp, vpar, offs, rank, csre);
    k_agg<<<2048, 256, 0, stream>>>(offs, csre, msg, aggb, bn_psum, bn_psq);
    k_bnfin<<<2, 256, 0, stream>>>(bn_psum, bn_psq, bng, bnbe, bns, bnbv);
    k_final<<<1563, 512, 0, stream>>>(aggb, bns, bnbv, w1p, b1, lng, lnb, w2p, b2, out);
}

// Round 17
// 265.104 us; speedup vs baseline: 1.0779x; 1.0216x over previous
//
#include <hip/hip_runtime.h>
#include <hip/hip_bf16.h>

#define NN 50000
#define EE 800000

typedef short short8 __attribute__((ext_vector_type(8)));
typedef float f32x4 __attribute__((ext_vector_type(4)));

union Frag16B { short8 s; int4 i; };
union H4 { _Float16 h[4]; uint2 u; };

static __device__ __forceinline__ unsigned short f2bf(float f) {
    union { float f; unsigned u; } v; v.f = f;
    unsigned r = v.u + 0x7FFF + ((v.u >> 16) & 1);   // RNE
    return (unsigned short)(r >> 16);
}
static __device__ __forceinline__ float bf_lo(unsigned int u) {
    return __uint_as_float(u << 16);
}
static __device__ __forceinline__ float bf_hi(unsigned int u) {
    return __uint_as_float(u & 0xFFFF0000u);
}
static __device__ __forceinline__ unsigned int pack2(float a, float b) {
    return (unsigned int)f2bf(a) | ((unsigned int)f2bf(b) << 16);
}

// ---------------- prep: weight packing + pos->float4 + workspace zeroing ----
__global__ __launch_bounds__(256) void k_prep(
    const float* __restrict__ w1,  const float* __restrict__ att,
    const float* __restrict__ w2,
    const float* __restrict__ wft, const float* __restrict__ wcv,
    const float* __restrict__ pos,
    unsigned short* __restrict__ w1p, unsigned short* __restrict__ w2p,
    unsigned short* __restrict__ wftp, unsigned short* __restrict__ wcvp,
    float4* __restrict__ pos4,
    int* __restrict__ counts, float* __restrict__ bn_psum, float* __restrict__ bn_psq)
{
    int gth = blockIdx.x * 256 + threadIdx.x;
    int lane = gth & 63, l15 = lane & 15, gg = lane >> 4;
    if (gth < 16384) {                       // w1p: kk<16, t<16, fold att[col]
        int t = (gth >> 6) & 15, kk = gth >> 10;
        int row = t * 16 + l15, c0 = kk * 32 + gg * 8;
        unsigned int pk[4];
        #pragma unroll
        for (int j = 0; j < 4; ++j) {
            int c = c0 + 2 * j;
            pk[j] = pack2(w1[row * 512 + c] * att[c],
                          w1[row * 512 + c + 1] * att[c + 1]);
        }
        *reinterpret_cast<uint4*>(w1p + (size_t)gth * 8) = make_uint4(pk[0], pk[1], pk[2], pk[3]);
        bn_psum[gth] = 0.f;
        bn_psq[gth] = 0.f;
    }
    if (gth < 4096) {                        // w2p: kk<8, t<8
        int t = (gth >> 6) & 7, kk = gth >> 9;
        int row = t * 16 + l15, c0 = kk * 32 + gg * 8;
        unsigned int pk[4];
        #pragma unroll
        for (int j = 0; j < 4; ++j) {
            int c = c0 + 2 * j;
            pk[j] = pack2(w2[row * 256 + c], w2[row * 256 + c + 1]);
        }
        *reinterpret_cast<uint4*>(w2p + (size_t)gth * 8) = make_uint4(pk[0], pk[1], pk[2], pk[3]);
    }
    if (gth < 2048) {                        // wftp / wcvp: kk<4, t<8
        int t = (gth >> 6) & 7, kk = gth >> 9;
        int row = t * 16 + l15, c0 = kk * 32 + gg * 8;
        unsigned int pa[4], pb[4];
        #pragma unroll
        for (int j = 0; j < 4; ++j) {
            int c = c0 + 2 * j;
            pa[j] = pack2(wft[row * 128 + c], wft[row * 128 + c + 1]);
            pb[j] = pack2(wcv[row * 128 + c], wcv[row * 128 + c + 1]);
        }
        *reinterpret_cast<uint4*>(wftp + (size_t)gth * 8) = make_uint4(pa[0], pa[1], pa[2], pa[3]);
        *reinterpret_cast<uint4*>(wcvp + (size_t)gth * 8) = make_uint4(pb[0], pb[1], pb[2], pb[3]);
    }
    if (gth < NN) {                          // pos -> padded float4; zero counts
        pos4[gth] = make_float4(pos[gth * 3 + 0], pos[gth * 3 + 1], pos[gth * 3 + 2], 0.f);
        counts[gth] = 0;
    }
}

// ---------------- fused: node GEMMs (blocks 0..781) || edge pass 1 (rest) ---
// The two kernels are independent (both depend only on k_prep) and have
// complementary profiles: ft_conv is MFMA-heavy, edge_pass1 is
// memory/atomic-heavy. Fusing them co-residents both block types so the CU
// scheduler overlaps matrix work with gather/atomic latency (grid-level
// analog of m114's MFMA+VALU wave co-scheduling). Edge blocks inherit the
// 34.8KB LDS allocation (4 blocks/CU) but edge_pass1 is atomic-throughput
// bound with 3125 blocks of slack.
__global__ __launch_bounds__(256) void k_ftc_edge(
    const float* __restrict__ x,
    const unsigned short* __restrict__ wftp, const float* __restrict__ bft,
    const unsigned short* __restrict__ wcvp, const float* __restrict__ bcv,
    unsigned int* __restrict__ msg,          // bf16 [NN][128] as uint[NN][64]
    const int* __restrict__ ei, const float4* __restrict__ pos4,
    float* __restrict__ blockmax, int* __restrict__ counts,
    int* __restrict__ rank)
{
    __shared__ unsigned int s_x[64 * 68];    // bf16 tile (reused for out)
    __shared__ unsigned short s_h[64 * 136];
    const int tid = threadIdx.x;

    if (blockIdx.x >= 782) {
        // -------------------- edge pass 1 --------------------
        float* smax = reinterpret_cast<float*>(s_x);
        int e = (blockIdx.x - 782) * 256 + tid;       // covers EE exactly
        int s = ei[e], d = ei[EE + e];
        float4 ps = pos4[s], pd = pos4[d];
        float dx = ps.x - pd.x, dy = ps.y - pd.y, dz = ps.z - pd.z;
        float dist = sqrtf(dx * dx + dy * dy + dz * dz);
        rank[e] = atomicAdd(&counts[d], 1);

        float m = dist;
        #pragma unroll
        for (int o = 32; o >= 1; o >>= 1)
            m = fmaxf(m, __shfl_xor(m, o));
        if ((tid & 63) == 0) smax[tid >> 6] = m;
        __syncthreads();
        if (tid == 0)
            blockmax[blockIdx.x - 782] = fmaxf(fmaxf(smax[0], smax[1]),
                                               fmaxf(smax[2], smax[3]));
        return;
    }

    // -------------------- ft_conv (col-split, R12) --------------------
    const int w = tid >> 6, lane = tid & 63, l15 = lane & 15, g = lane >> 4;
    const int n0 = blockIdx.x * 64;

    #pragma unroll
    for (int i = 0; i < 8; ++i) {
        int lin = tid + i * 256;
        int row = lin >> 5, c4 = lin & 31;
        int ar = (n0 + row < NN) ? n0 + row : NN - 1;
        float4 v = *reinterpret_cast<const float4*>(x + (size_t)ar * 128 + c4 * 4);
        s_x[row * 68 + c4 * 2]     = pack2(v.x, v.y);
        s_x[row * 68 + c4 * 2 + 1] = pack2(v.z, v.w);
    }
    __syncthreads();

    float bftv[2], bcvv[2];
    #pragma unroll
    for (int t = 0; t < 2; ++t) {
        bftv[t] = bft[(w * 2 + t) * 16 + l15];
        bcvv[t] = bcv[(w * 2 + t) * 16 + l15];
    }

    const int4* Bf = reinterpret_cast<const int4*>(wftp);
    f32x4 acc[8];                            // [rt*2 + t]
    #pragma unroll
    for (int i = 0; i < 8; ++i) acc[i] = (f32x4){0.f, 0.f, 0.f, 0.f};
    #pragma unroll
    for (int kk = 0; kk < 4; ++kk) {
        Frag16B b[2];
        #pragma unroll
        for (int t = 0; t < 2; ++t)
            b[t].i = Bf[(kk * 8 + w * 2 + t) * 64 + lane];
        Frag16B a[4];
        #pragma unroll
        for (int rt = 0; rt < 4; ++rt)
            a[rt].i = *reinterpret_cast<const int4*>(
                &s_x[(rt * 16 + l15) * 68 + kk * 16 + g * 4]);
        #pragma unroll
        for (int rt = 0; rt < 4; ++rt)
            #pragma unroll
            for (int t = 0; t < 2; ++t)
                acc[rt * 2 + t] = __builtin_amdgcn_mfma_f32_16x16x32_bf16(
                    a[rt].s, b[t].s, acc[rt * 2 + t], 0, 0, 0);
    }
    #pragma unroll
    for (int rt = 0; rt < 4; ++rt)
        #pragma unroll
        for (int t = 0; t < 2; ++t)
            #pragma unroll
            for (int r = 0; r < 4; ++r)
                s_h[(rt * 16 + g * 4 + r) * 136 + (w * 2 + t) * 16 + l15] =
                    f2bf(fmaxf(acc[rt * 2 + t][r] + bftv[t], 0.f));
    __syncthreads();

    const int4* Bc = reinterpret_cast<const int4*>(wcvp);
    #pragma unroll
    for (int i = 0; i < 8; ++i) acc[i] = (f32x4){0.f, 0.f, 0.f, 0.f};
    #pragma unroll
    for (int kk = 0; kk < 4; ++kk) {
        Frag16B b[2];
        #pragma unroll
        for (int t = 0; t < 2; ++t)
            b[t].i = Bc[(kk * 8 + w * 2 + t) * 64 + lane];
        Frag16B a[4];
        #pragma unroll
        for (int rt = 0; rt < 4; ++rt)
            a[rt].i = *reinterpret_cast<const int4*>(
                &s_h[(rt * 16 + l15) * 136 + kk * 32 + g * 8]);
        #pragma unroll
        for (int rt = 0; rt < 4; ++rt)
            #pragma unroll
            for (int t = 0; t < 2; ++t)
                acc[rt * 2 + t] = __builtin_amdgcn_mfma_f32_16x16x32_bf16(
                    a[rt].s, b[t].s, acc[rt * 2 + t], 0, 0, 0);
    }
    unsigned short* s_o = reinterpret_cast<unsigned short*>(s_x);
    #pragma unroll
    for (int rt = 0; rt < 4; ++rt)
        #pragma unroll
        for (int t = 0; t < 2; ++t)
            #pragma unroll
            for (int r = 0; r < 4; ++r)
                s_o[(rt * 16 + g * 4 + r) * 136 + (w * 2 + t) * 16 + l15] =
                    f2bf(acc[rt * 2 + t][r] + bcvv[t]);
    __syncthreads();
    #pragma unroll
    for (int i = 0; i < 8; ++i) {
        int lin = tid + i * 256;
        int row = lin >> 5, cu2 = lin & 31;
        if (n0 + row < NN) {
            uint2 v;
            v.x = s_x[row * 68 + cu2 * 2];
            v.y = s_x[row * 68 + cu2 * 2 + 1];
            *reinterpret_cast<uint2*>(msg + (size_t)(n0 + row) * 64 + cu2 * 2) = v;
        }
    }
}

// ---------------- scan 1: per-block inclusive scan of counts ----------------
__global__ __launch_bounds__(256) void k_scan1(const int* __restrict__ counts,
    int* __restrict__ loc, int* __restrict__ bsum)
{
    __shared__ int sd[256];
    int i = blockIdx.x * 256 + threadIdx.x;
    int v = (i < NN) ? counts[i] : 0;
    sd[threadIdx.x] = v;
    __syncthreads();
    for (int ofs = 1; ofs < 256; ofs <<= 1) {
        int t = (threadIdx.x >= ofs) ? sd[threadIdx.x - ofs] : 0;
        __syncthreads();
        sd[threadIdx.x] += t;
        __syncthreads();
    }
    int incl = sd[threadIdx.x];
    if (i < NN) loc[i] = incl - v;
    if (threadIdx.x == 255) bsum[blockIdx.x] = incl;
}

// ---------------- scan 2 (merged): offs with inline bofs + dmax block -------
__global__ __launch_bounds__(256) void k_scan3(const int* __restrict__ loc,
    const int* __restrict__ bsum, const float* __restrict__ blockmax,
    int* __restrict__ offs, float* __restrict__ dmax, int nmb)
{
    if (blockIdx.x < 196) {
        __shared__ int sd[256];
        __shared__ int s_v[256];
        int v = (threadIdx.x < 196) ? bsum[threadIdx.x] : 0;
        sd[threadIdx.x] = v;
        s_v[threadIdx.x] = v;
        __syncthreads();
        for (int ofs = 1; ofs < 256; ofs <<= 1) {
            int t = (threadIdx.x >= ofs) ? sd[threadIdx.x - ofs] : 0;
            __syncthreads();
            sd[threadIdx.x] += t;
            __syncthreads();
        }
        int bofs = sd[blockIdx.x] - s_v[blockIdx.x];   // exclusive prefix at this block
        int i = blockIdx.x * 256 + threadIdx.x;
        if (i < NN) offs[i] = loc[i] + bofs;
        if (i == 0) offs[NN] = EE;
    } else {
        __shared__ float smax[4];
        float m = 0.f;
        for (int i = threadIdx.x; i < nmb; i += 256) m = fmaxf(m, blockmax[i]);
        #pragma unroll
        for (int o = 32; o >= 1; o >>= 1)
            m = fmaxf(m, __shfl_xor(m, o));
        if ((threadIdx.x & 63) == 0) smax[threadIdx.x >> 6] = m;
        __syncthreads();
        if (threadIdx.x == 0)
            dmax[0] = fmaxf(fmaxf(smax[0], smax[1]), fmaxf(smax[2], smax[3]));
    }
}

// ---------------- edge pass 2: geometry + ab + AoS CSR record ---------------
__global__ __launch_bounds__(256) void k_fill(
    const int* __restrict__ ei, const float4* __restrict__ pos4,
    const float* __restrict__ dmaxp,
    const float* __restrict__ vfp, const float* __restrict__ vpar,
    const int* __restrict__ offs, const int* __restrict__ rank,
    uint4* __restrict__ csre)
{
    int e = blockIdx.x * 256 + threadIdx.x;       // grid covers EE exactly
    int s = ei[e], d = ei[EE + e];
    float4 ps = pos4[s], pd = pos4[d];
    float dx = ps.x - pd.x, dy = ps.y - pd.y, dz = ps.z - pd.z;
    float dist = sqrtf(dx * dx + dy * dy + dz * dz);
    float rinv = 1.f / (dist + 1e-8f);
    float dsum = (dx + dy + dz) * rinv;
    float r = dist / dmaxp[0];
    float vf = vfp[0];
    H4 p;
    #pragma unroll
    for (int k = 0; k < 4; ++k) {
        float v = vf * fminf(r, vpar[k]);
        p.h[k] = (_Float16)(sqrtf(1.f - v * v + 1e-8f) / (1.f + v * dsum));
    }
    int slot = offs[d] + rank[e];
    csre[slot] = make_uint4((unsigned)s, p.u.x, p.u.y, 0u);
}

// ---------------- aggregation + fused BN partial stats ----------------------
// R8 structure (locally converged). AoS csre records, wave-uniform indices.
__global__ __launch_bounds__(256) void k_agg(
    const int* __restrict__ offs, const uint4* __restrict__ csre,
    const unsigned int* __restrict__ msg,
    unsigned int* __restrict__ aggb,         // bf16 [NN][512] as uint[NN][256]
    float* __restrict__ bn_psum, float* __restrict__ bn_psq)
{
    __shared__ float s_bn[4 * 1024];         // [wave][16 vals][64 lanes]
    const int tid = threadIdx.x;
    const int lane = tid & 63;
    const int w = __builtin_amdgcn_readfirstlane(tid >> 6);
    const int gw = (blockIdx.x << 2) | w;    // 0..8191

    float ps0 = 0, ps1 = 0, ps2 = 0, ps3 = 0, ps4 = 0, ps5 = 0, ps6 = 0, ps7 = 0;
    float pq0 = 0, pq1 = 0, pq2 = 0, pq3 = 0, pq4 = 0, pq5 = 0, pq6 = 0, pq7 = 0;

    for (int n = gw; n < NN; n += 8192) {
        int st = __builtin_amdgcn_readfirstlane(offs[n]);
        int en = __builtin_amdgcn_readfirstlane(offs[n + 1]);
        float a00 = 0, a10 = 0, a20 = 0, a30 = 0, a01 = 0, a11 = 0, a21 = 0, a31 = 0;

        for (int e = st; e < en; e += 8) {
            int idx[8];
            uint4 rr[8];
            unsigned int uu[8];
            #pragma unroll
            for (int j = 0; j < 8; ++j) {
                int ee = e + j;
                idx[j] = (ee < en) ? ee : en - 1;       // wave-uniform clamp
            }
            #pragma unroll
            for (int j = 0; j < 8; ++j) rr[j] = csre[idx[j]];
            #pragma unroll
            for (int j = 0; j < 8; ++j)
                uu[j] = msg[(size_t)rr[j].x * 64 + lane];
            #pragma unroll
            for (int j = 0; j < 8; ++j) {
                bool valid = (e + j) < en;              // wave-uniform
                H4 p;
                p.u.x = valid ? rr[j].y : 0u;
                p.u.y = valid ? rr[j].z : 0u;
                float m0 = bf_lo(uu[j]), m1 = bf_hi(uu[j]);
                a00 = fmaf((float)p.h[0], m0, a00); a01 = fmaf((float)p.h[0], m1, a01);
                a10 = fmaf((float)p.h[1], m0, a10); a11 = fmaf((float)p.h[1], m1, a11);
                a20 = fmaf((float)p.h[2], m0, a20); a21 = fmaf((float)p.h[2], m1, a21);
                a30 = fmaf((float)p.h[3], m0, a30); a31 = fmaf((float)p.h[3], m1, a31);
            }
        }

        unsigned int* o = aggb + (size_t)n * 256 + lane;   // col c = k*128 + h
        o[0]   = pack2(a00, a01);
        o[64]  = pack2(a10, a11);
        o[128] = pack2(a20, a21);
        o[192] = pack2(a30, a31);

        ps0 += a00; pq0 = fmaf(a00, a00, pq0);
        ps1 += a01; pq1 = fmaf(a01, a01, pq1);
        ps2 += a10; pq2 = fmaf(a10, a10, pq2);
        ps3 += a11; pq3 = fmaf(a11, a11, pq3);
        ps4 += a20; pq4 = fmaf(a20, a20, pq4);
        ps5 += a21; pq5 = fmaf(a21, a21, pq5);
        ps6 += a30; pq6 = fmaf(a30, a30, pq6);
        ps7 += a31; pq7 = fmaf(a31, a31, pq7);
    }

    // per-wave partials -> LDS
    float* sw = s_bn + w * 1024 + lane;
    sw[0 * 64] = ps0; sw[1 * 64] = ps1; sw[2 * 64] = ps2; sw[3 * 64] = ps3;
    sw[4 * 64] = ps4; sw[5 * 64] = ps5; sw[6 * 64] = ps6; sw[7 * 64] = ps7;
    sw[8 * 64] = pq0; sw[9 * 64] = pq1; sw[10 * 64] = pq2; sw[11 * 64] = pq3;
    sw[12 * 64] = pq4; sw[13 * 64] = pq5; sw[14 * 64] = pq6; sw[15 * 64] = pq7;
    __syncthreads();

    // cross-wave reduce + one atomic per entry (1024 entries / 256 threads)
    int part = (blockIdx.x & 31) * 512;
    #pragma unroll
    for (int k = 0; k < 4; ++k) {
        int idx = tid + k * 256;                 // 0..1023
        float s = s_bn[idx] + s_bn[1024 + idx] + s_bn[2048 + idx] + s_bn[3072 + idx];
        int v = idx >> 6, ln = idx & 63;
        int col = ((v & 7) >> 1) * 128 + 2 * ln + (v & 1);
        if (v < 8) atomicAdd(&bn_psum[part + col], s);
        else       atomicAdd(&bn_psq[part + col], s);
    }
}

__global__ __launch_bounds__(256) void k_bnfin(const float* __restrict__ bn_psum,
    const float* __restrict__ bn_psq, const float* __restrict__ bng,
    const float* __restrict__ bnbeta, float* __restrict__ bns, float* __restrict__ bnbv)
{
    int c = blockIdx.x * 256 + threadIdx.x;
    if (c >= 512) return;
    float s = 0.f, q = 0.f;
    #pragma unroll 8
    for (int p = 0; p < 32; ++p) {
        s += bn_psum[p * 512 + c];
        q += bn_psq[p * 512 + c];
    }
    float mean = s * (1.f / NN);
    float var = q * (1.f / NN) - mean * mean;
    float sc = bng[c] / sqrtf(var + 1e-5f);
    bns[c] = sc;
    bnbv[c] = bnbeta[c] - mean * sc;
}

// ---------------- final fused MFMA: 8 waves; GEMM2 full-sector stores -------
__global__ __launch_bounds__(512, 8) void k_final(
    const unsigned int* __restrict__ aggb,
    const float* __restrict__ bns, const float* __restrict__ bnb,
    const unsigned short* __restrict__ w1p, const float* __restrict__ b1,
    const float* __restrict__ lng, const float* __restrict__ lnb,
    const unsigned short* __restrict__ w2p, const float* __restrict__ b2,
    float* __restrict__ out)
{
    __shared__ unsigned int s_z[32 * 260];   // 33280 B; t matrix aliases below
    __shared__ float s_lng[256], s_lnb[256];
    __shared__ float s_ps[8][32], s_pq[8][32];
    __shared__ float s_mu[32], s_iv[32];
    unsigned short* s_ts = reinterpret_cast<unsigned short*>(s_z);  // [32][264]

    const int tid = threadIdx.x;
    const int w = tid >> 6, lane = tid & 63, l15 = lane & 15, g = lane >> 4;
    const int n0 = blockIdx.x * 32;

    if (tid < 256) {
        s_lng[tid] = lng[tid];
        s_lnb[tid] = lnb[tid];
    }

    // stage z = bf16(relu(agg*scale+shift)); uint4: thread owns ucols 4t..4t+3
    const int t6 = tid & 63, r0 = tid >> 6;
    f32x4 sva = *reinterpret_cast<const f32x4*>(bns + 8 * t6);
    f32x4 svb = *reinterpret_cast<const f32x4*>(bns + 8 * t6 + 4);
    f32x4 bva = *reinterpret_cast<const f32x4*>(bnb + 8 * t6);
    f32x4 bvb = *reinterpret_cast<const f32x4*>(bnb + 8 * t6 + 4);
    #pragma unroll
    for (int i = 0; i < 4; ++i) {
        int row = i * 8 + r0;
        int ar = (n0 + row < NN) ? n0 + row : NN - 1;
        uint4 u = *reinterpret_cast<const uint4*>(aggb + (size_t)ar * 256 + t6 * 4);
        uint4 o;
        o.x = pack2(fmaxf(fmaf(bf_lo(u.x), sva[0], bva[0]), 0.f),
                    fmaxf(fmaf(bf_hi(u.x), sva[1], bva[1]), 0.f));
        o.y = pack2(fmaxf(fmaf(bf_lo(u.y), sva[2], bva[2]), 0.f),
                    fmaxf(fmaf(bf_hi(u.y), sva[3], bva[3]), 0.f));
        o.z = pack2(fmaxf(fmaf(bf_lo(u.z), svb[0], bvb[0]), 0.f),
                    fmaxf(fmaf(bf_hi(u.z), svb[1], bvb[1]), 0.f));
        o.w = pack2(fmaxf(fmaf(bf_lo(u.w), svb[2], bvb[2]), 0.f),
                    fmaxf(fmaf(bf_hi(u.w), svb[3], bvb[3]), 0.f));
        *reinterpret_cast<uint4*>(&s_z[row * 260 + t6 * 4]) = o;
    }
    __syncthreads();

    // ---------------- GEMM1: 2 row-tiles x 2 j-tiles, B block-unique --------
    const int4* B1 = reinterpret_cast<const int4*>(w1p);
    f32x4 acc1[4];                           // [rt*2 + j]
    #pragma unroll
    for (int i = 0; i < 4; ++i) acc1[i] = (f32x4){0.f, 0.f, 0.f, 0.f};

    #pragma unroll 2
    for (int kk = 0; kk < 16; ++kk) {
        Frag16B b[2];
        #pragma unroll
        for (int j = 0; j < 2; ++j)
            b[j].i = B1[(kk * 16 + w * 2 + j) * 64 + lane];
        Frag16B a[2];
        #pragma unroll
        for (int rt = 0; rt < 2; ++rt)
            a[rt].i = *reinterpret_cast<const int4*>(
                &s_z[(rt * 16 + l15) * 260 + kk * 16 + g * 4]);
        #pragma unroll
        for (int rt = 0; rt < 2; ++rt)
            #pragma unroll
            for (int j = 0; j < 2; ++j)
                acc1[rt * 2 + j] = __builtin_amdgcn_mfma_f32_16x16x32_bf16(
                    a[rt].s, b[j].s, acc1[rt * 2 + j], 0, 0, 0);
    }
    __syncthreads();   // all z reads done before t overwrites the buffer

    // ---------------- bias + t stash + LN partials (per col-eighth) ---------
    float b1v[2];
    #pragma unroll
    for (int j = 0; j < 2; ++j) b1v[j] = b1[(w * 2 + j) * 16 + l15];

    float ssum[8], ssq[8];                   // [rt*4 + r]
    #pragma unroll
    for (int i = 0; i < 8; ++i) { ssum[i] = 0.f; ssq[i] = 0.f; }
    #pragma unroll
    for (int rt = 0; rt < 2; ++rt)
        #pragma unroll
        for (int j = 0; j < 2; ++j) {
            float bvv = b1v[j];
            #pragma unroll
            for (int r = 0; r < 4; ++r) {
                float tv = acc1[rt * 2 + j][r] + bvv;
                ssum[rt * 4 + r] += tv;
                ssq[rt * 4 + r] = fmaf(tv, tv, ssq[rt * 4 + r]);
                s_ts[(rt * 16 + g * 4 + r) * 264 + (w * 2 + j) * 16 + l15] = f2bf(tv);
            }
        }
    #pragma unroll
    for (int m = 1; m < 16; m <<= 1) {
        #pragma unroll
        for (int i = 0; i < 8; ++i) {
            ssum[i] += __shfl_xor(ssum[i], m);
            ssq[i]  += __shfl_xor(ssq[i], m);
        }
    }
    if (l15 == 0) {
        #pragma unroll
        for (int rt = 0; rt < 2; ++rt)
            #pragma unroll
            for (int r = 0; r < 4; ++r) {
                s_ps[w][rt * 16 + g * 4 + r] = ssum[rt * 4 + r];
                s_pq[w][rt * 16 + g * 4 + r] = ssq[rt * 4 + r];
            }
    }
    __syncthreads();

    if (tid < 32) {
        float s = 0.f, q = 0.f;
        #pragma unroll
        for (int p = 0; p < 8; ++p) { s += s_ps[p][tid]; q += s_pq[p][tid]; }
        float mean = s * (1.f / 256.f);
        float var = q * (1.f / 256.f) - mean * mean;
        s_mu[tid] = mean;
        s_iv[tid] = 1.f / sqrtf(var + 1e-5f);
    }
    __syncthreads();

    // ---------------- GEMM2: wave (rt,jp) = (w>>2, w&3); 2 adjacent j-tiles -
    const int rt2 = w >> 2, jp = w & 3;
    const float mu_s = s_mu[rt2 * 16 + l15];
    const float iv_s = s_iv[rt2 * 16 + l15];
    const int4* B2 = reinterpret_cast<const int4*>(w2p);
    const unsigned short* trow = s_ts + (rt2 * 16 + l15) * 264;

    f32x4 acc2[2];                           // [j]
    #pragma unroll
    for (int i = 0; i < 2; ++i) acc2[i] = (f32x4){0.f, 0.f, 0.f, 0.f};

    #pragma unroll 2
    for (int kk = 0; kk < 8; ++kk) {
        const int kb = kk * 32 + g * 8;
        Frag16B b[2];
        #pragma unroll
        for (int j = 0; j < 2; ++j)
            b[j].i = B2[(kk * 8 + jp * 2 + j) * 64 + lane];
        int4 traw = *reinterpret_cast<const int4*>(trow + kb);
        const unsigned short* tu = reinterpret_cast<const unsigned short*>(&traw);
        short8 af;
        #pragma unroll
        for (int jj = 0; jj < 8; ++jj) {
            float tv = __uint_as_float(((unsigned int)tu[jj]) << 16);
            float rn = fmaxf(fmaf((tv - mu_s) * iv_s, s_lng[kb + jj], s_lnb[kb + jj]), 0.f);
            af[jj] = (short)f2bf(rn);
        }
        #pragma unroll
        for (int j = 0; j < 2; ++j)
            acc2[j] = __builtin_amdgcn_mfma_f32_16x16x32_bf16(
                af, b[j].s, acc2[j], 0, 0, 0);
    }

    float b2v[2];
    #pragma unroll
    for (int j = 0; j < 2; ++j) b2v[j] = b2[(jp * 2 + j) * 16 + l15];

    #pragma unroll
    for (int j = 0; j < 2; ++j)
        #pragma unroll
        for (int r = 0; r < 4; ++r) {
            int n = n0 + rt2 * 16 + g * 4 + r;
            if (n < NN)
                out[(size_t)n * 128 + (jp * 2 + j) * 16 + l15] = acc2[j][r] + b2v[j];
        }
}

// ---------------------------------------------------------------------------
extern "C" void kernel_launch(void* const* d_in, const int* in_sizes, int n_in,
                              void* d_out, int out_size, void* d_ws, size_t ws_size,
                              hipStream_t stream)
{
    const float* x    = (const float*)d_in[0];
    const int*   ei   = (const int*)d_in[1];
    const float* pos  = (const float*)d_in[2];
    const float* wft  = (const float*)d_in[3];
    const float* bft  = (const float*)d_in[4];
    const float* wcv  = (const float*)d_in[5];
    const float* bcv  = (const float*)d_in[6];
    const float* vfp  = (const float*)d_in[7];
    const float* vpar = (const float*)d_in[8];
    const float* bng  = (const float*)d_in[9];
    const float* bnbe = (const float*)d_in[10];
    const float* att  = (const float*)d_in[11];
    const float* w1   = (const float*)d_in[12];
    const float* b1   = (const float*)d_in[13];
    const float* lng  = (const float*)d_in[14];
    const float* lnb  = (const float*)d_in[15];
    const float* w2   = (const float*)d_in[16];
    const float* b2   = (const float*)d_in[17];
    float* out = (float*)d_out;

    float* ws = (float*)d_ws;
    size_t off = 0;
    unsigned int* msg  = (unsigned int*)(ws + off); off += (size_t)NN * 64;    // bf16 [N][128]
    unsigned int* aggb = (unsigned int*)(ws + off); off += (size_t)NN * 256;   // bf16 [N][512]
    unsigned short* w1p  = (unsigned short*)(ws + off); off += 65536;
    unsigned short* w2p  = (unsigned short*)(ws + off); off += 16384;
    unsigned short* wftp = (unsigned short*)(ws + off); off += 8192;
    unsigned short* wcvp = (unsigned short*)(ws + off); off += 8192;
    float4* pos4 = (float4*)(ws + off); off += (size_t)NN * 4;
    float* bns  = ws + off; off += 512;
    float* bnbv = ws + off; off += 512;
    uint4* csre = (uint4*)(ws + off); off += (size_t)EE * 4;    // AoS: {src, ab01, ab23, pad}
    int* rank   = (int*)(ws + off); off += (size_t)EE;          // per-edge CSR rank
    int* offs   = (int*)(ws + off); off += NN + 4;
    int* loc    = (int*)(ws + off); off += NN;
    int* bsum   = (int*)(ws + off); off += 256;
    float* blockmax = ws + off; off += 3136;
    float* dmax = ws + off; off += 4;
    float* bn_psum = ws + off; off += 32 * 512;
    float* bn_psq  = ws + off; off += 32 * 512;
    int* counts = (int*)(ws + off); off += NN;

    k_prep<<<196, 256, 0, stream>>>(w1, att, w2, wft, wcv, pos, w1p, w2p, wftp, wcvp,
                                    pos4, counts, bn_psum, bn_psq);
    k_ftc_edge<<<3907, 256, 0, stream>>>(x, wftp, bft, wcvp, bcv, msg,
                                         ei, pos4, blockmax, counts, rank);
    k_scan1<<<196, 256, 0, stream>>>(counts, loc, bsum);
    k_scan3<<<197, 256, 0, stream>>>(loc, bsum, blockmax, offs, dmax, 3125);
    k_fill<<<3125, 256, 0, stream>>>(ei, pos4, dmax, vfp, vpar, offs, rank, csre);
    k_agg<<<2048, 256, 0, stream>>>(offs, csre, msg, aggb, bn_psum, bn_psq);
    k_bnfin<<<2, 256, 0, stream>>>(bn_psum, bn_psq, bng, bnbe, bns, bnbv);
    k_final<<<1563, 512, 0, stream>>>(aggb, bns, bnbv, w1p, b1, lng, lnb, w2p, b2, out);
}